// Round 9
// baseline (338.816 us; speedup 1.0000x reference)
//
#include <hip/hip_runtime.h>
#include <stdint.h>

#define N_ANCH 102400
#define FMP 320
#define K_TOP 1000
#define NMS_T 0.6f
#define SC_CLAMP 6.907755278982137f
#define IMGF 1280.0f
#define NBINS 16384   // scores in (0,1) => float bits>>16 < 0x4000
#define NBLK2 100
#define NTHR2 1024

// ---- workspace layout (bytes) ----
#define OFF_SCORES   0u          // f32[102400]
#define OFF_LABELS   409600u     // u32[102400]
#define OFF_HIST     819200u     // u32[16384]
#define OFF_META     884736u     // u32[64]: [2]=cand ctr [8..11]=barrier counters
#define OFF_KEYS     884992u     // u64[4096]
#define OFF_BOXES    917760u     // f32[4000]
#define OFF_LAB1K    933760u     // u32[1000]
#define OFF_MASK     937760u     // u64[16000]
#define OFF_DIAG     1065760u    // u64[1024]

__device__ __forceinline__ float sigf(float x) {
    return 1.0f / (1.0f + expf(-x));
}

// Device-scope spin barrier for a co-resident grid (NBLK2 blocks, 64KB LDS
// => residency guaranteed on 256 CUs).
__device__ __forceinline__ void gbar(uint32_t* ctr, uint32_t target) {
    __threadfence();
    __syncthreads();
    if (threadIdx.x == 0) {
        atomicAdd(ctr, 1u);
        while (atomicAdd(ctr, 0u) < target) __builtin_amdgcn_s_sleep(10);
    }
    __syncthreads();
    __threadfence();
}

// ---------------- K1: scores+argmax; fused zeroing of hist/meta/diag ----------------
__global__ __launch_bounds__(256) void k_scores(const float* __restrict__ hmp,
                                                const float* __restrict__ iou,
                                                float* __restrict__ scores,
                                                uint32_t* __restrict__ labels,
                                                uint32_t* __restrict__ hist,
                                                uint32_t* __restrict__ meta,
                                                uint64_t* __restrict__ diag) {
    int blk = blockIdx.x;
    if (blk < 64) {
        hist[blk * 256 + threadIdx.x] = 0u;
    } else if (blk == 64) {
        if (threadIdx.x < 64) meta[threadIdx.x] = 0u;
#pragma unroll
        for (int k = 0; k < 4; ++k) diag[threadIdx.x * 4 + k] = 0ull;
    }
    int gid = blk * 256 + threadIdx.x;
    int a = gid >> 2;
    int q = gid & 3;
    float si = sigf(iou[a]);
    const float4* row4 = (const float4*)hmp + (size_t)a * 20 + q;
    float4 v[5];
#pragma unroll
    for (int j = 0; j < 5; ++j) v[j] = row4[j * 4];
    float best = -1.0f;
    int bc = 0;
#pragma unroll
    for (int j = 0; j < 5; ++j) {
        int cb = j * 16 + q * 4;
        float f;
        f = sqrtf(sigf(v[j].x) * si); if (f > best) { best = f; bc = cb; }
        f = sqrtf(sigf(v[j].y) * si); if (f > best) { best = f; bc = cb + 1; }
        f = sqrtf(sigf(v[j].z) * si); if (f > best) { best = f; bc = cb + 2; }
        f = sqrtf(sigf(v[j].w) * si); if (f > best) { best = f; bc = cb + 3; }
    }
#pragma unroll
    for (int off = 1; off <= 2; off <<= 1) {
        float of = __shfl_xor(best, off);
        int   oc = __shfl_xor(bc, off);
        if (of > best || (of == best && oc < bc)) { best = of; bc = oc; }
    }
    if (q == 0) {
        scores[a] = best;
        labels[a] = (uint32_t)bc;
    }
}

// ---------------- K2: everything else, 100 blocks x 1024, 4 spin barriers ----------------
__global__ __launch_bounds__(NTHR2, 4) void k_mega(const float* __restrict__ scores,
                                                   const uint32_t* __restrict__ labels,
                                                   const float* __restrict__ reg,
                                                   uint32_t* __restrict__ hist,
                                                   uint32_t* __restrict__ meta,
                                                   uint64_t* __restrict__ keys,
                                                   float* __restrict__ boxes,
                                                   uint32_t* __restrict__ lab1k,
                                                   uint64_t* __restrict__ mask,
                                                   uint64_t* __restrict__ diag,
                                                   float* __restrict__ out) {
    __shared__ __align__(16) uint32_t sh32[NBINS];   // 64 KB, reused per phase
    uint64_t* sk = (uint64_t*)sh32;                  // phase-4 view (4096 u64)
    const int tid  = threadIdx.x;
    const int blk  = blockIdx.x;
    const int gtid = blk * NTHR2 + tid;              // exactly covers 102400
    const int lane = tid & 63;
    const int wv   = tid >> 6;

    // ===== P1: LDS-private histogram of this block's 1024 scores =====
    for (int i = tid; i < NBINS; i += NTHR2) sh32[i] = 0u;
    __syncthreads();
    uint32_t mybits = __float_as_uint(scores[gtid]);
    atomicAdd(&sh32[mybits >> 16], 1u);
    __syncthreads();
    for (int i = tid; i < NBINS; i += NTHR2) {
        uint32_t c = sh32[i];
        if (c) atomicAdd(&hist[i], c);
    }
    gbar(&meta[8], NBLK2);   // ---- global hist complete

    // ===== P2: cutoff, computed redundantly by every block (no 2nd barrier) =====
    {
        uint32_t s = 0;
#pragma unroll
        for (int b = 0; b < 16; ++b) s += hist[tid * 16 + b];
        sh32[tid] = s;
        __syncthreads();
        for (int off = 1; off < NTHR2; off <<= 1) {
            uint32_t v = sh32[tid] + ((tid + off < NTHR2) ? sh32[tid + off] : 0u);
            __syncthreads();
            sh32[tid] = v;
            __syncthreads();
        }
        uint32_t inc   = sh32[tid];
        uint32_t above = (tid < NTHR2 - 1) ? sh32[tid + 1] : 0u;
        if (above < K_TOP && inc >= K_TOP) {
            uint32_t loc[16];
#pragma unroll
            for (int b = 0; b < 16; ++b) loc[b] = hist[tid * 16 + b];
            uint32_t cnt = above;
            for (int b = 15; b >= 0; --b) {
                cnt += loc[b];
                if (cnt >= K_TOP) { sh32[1025] = (uint32_t)(tid * 16 + b); break; }
            }
        }
        __syncthreads();
    }
    uint32_t cutoff = sh32[1025];
    __syncthreads();

    // ===== P3: collect this block's candidates (block-aggregated append) =====
    if (tid == 0) sh32[0] = 0u;
    __syncthreads();
    bool cand = (mybits >> 16) >= cutoff;
    uint32_t pos = 0;
    if (cand) pos = atomicAdd(&sh32[0], 1u);
    __syncthreads();
    if (tid == 0) sh32[1] = sh32[0] ? atomicAdd(&meta[2], sh32[0]) : 0u;
    __syncthreads();
    if (cand) {
        uint32_t p = sh32[1] + pos;
        if (p < 4096u)
            keys[p] = ((uint64_t)mybits << 32) | (uint64_t)(0xFFFFFFFFu - (uint32_t)gtid);
    }
    gbar(&meta[9], NBLK2);   // ---- keys complete

    // ===== P4: rank (wave per candidate) + decode epilogue =====
    {
        uint32_t M = meta[2];
        if (M > 4096u) M = 4096u;
        for (uint32_t i = tid; i < M; i += NTHR2) sk[i] = keys[i];
        __syncthreads();
        for (uint32_t wg = (uint32_t)(blk * 16 + wv); wg < M; wg += NBLK2 * 16) {
            uint64_t mykey = sk[wg];
            uint32_t rank = 0;
            for (uint32_t j = lane; j < M; j += 64) rank += (sk[j] > mykey) ? 1u : 0u;
#pragma unroll
            for (int off = 32; off; off >>= 1) rank += __shfl_xor(rank, off);
            if (lane == 0 && rank < K_TOP) {
                int t = (int)rank;
                uint32_t sbits = (uint32_t)(mykey >> 32);
                uint32_t idx   = 0xFFFFFFFFu - (uint32_t)(mykey & 0xFFFFFFFFull);
                float score = __uint_as_float(sbits);
                uint32_t lab = labels[idx];
                out[t]         = score;
                out[K_TOP + t] = (float)lab;
                lab1k[t]       = lab;
                float ax = (float)(idx % FMP);
                float ay = (float)(idx / FMP);
                float4 rr = ((const float4*)reg)[idx];
                float e0 = expf(fminf(rr.x, SC_CLAMP));
                float e1 = expf(fminf(rr.y, SC_CLAMP));
                float e2 = expf(fminf(rr.z, SC_CLAMP));
                float e3 = expf(fminf(rr.w, SC_CLAMP));
                float x1 = fminf(fmaxf((ax - e0) * 4.0f / IMGF, 0.0f), 1.0f);
                float y1 = fminf(fmaxf((ay - e1) * 4.0f / IMGF, 0.0f), 1.0f);
                float x2 = fminf(fmaxf((ax + e2) * 4.0f / IMGF, 0.0f), 1.0f);
                float y2 = fminf(fmaxf((ay + e3) * 4.0f / IMGF, 0.0f), 1.0f);
                out[2 * K_TOP + t * 4 + 0] = x1;
                out[2 * K_TOP + t * 4 + 1] = y1;
                out[2 * K_TOP + t * 4 + 2] = x2;
                out[2 * K_TOP + t * 4 + 3] = y2;
                boxes[t * 4 + 0] = x1;
                boxes[t * 4 + 1] = y1;
                boxes[t * 4 + 2] = x2;
                boxes[t * 4 + 3] = y2;
            }
        }
    }
    gbar(&meta[10], NBLK2);   // ---- boxes/lab1k ready

    // ===== P5: suppress masks, one wave per row =====
    {
        int r = blk * 16 + wv;
        if (r < K_TOP) {
            float4 bi = ((const float4*)boxes)[r];
            uint32_t li = lab1k[r];
            float areai = (bi.z - bi.x) * (bi.w - bi.y);
            int iw = r >> 6;
            uint64_t dw = 0ull;
#pragma unroll
            for (int w = 0; w < 16; ++w) {
                int j = w * 64 + lane;
                bool sup = false;
                if (j < K_TOP && j > r) {
                    float4 bj = ((const float4*)boxes)[j];
                    float areaj = (bj.z - bj.x) * (bj.w - bj.y);
                    float xx1 = fmaxf(bi.x, bj.x);
                    float yy1 = fmaxf(bi.y, bj.y);
                    float xx2 = fminf(bi.z, bj.z);
                    float yy2 = fminf(bi.w, bj.w);
                    float ww = fmaxf(1e-10f, xx2 - xx1);
                    float hh = fmaxf(1e-10f, yy2 - yy1);
                    float inter = ww * hh;
                    float iouv = inter / (areai + areaj - inter + 1e-10f);
                    sup = (iouv > NMS_T) && (li == lab1k[j]);
                }
                unsigned long long m = __ballot(sup);
                if (lane == 0) mask[(size_t)r * 16 + w] = (uint64_t)m;
                if (w == iw) dw = (uint64_t)m;
            }
            if (lane == 0) diag[r] = dw;
        }
    }
    gbar(&meta[11], NBLK2);   // ---- masks + diag ready

    // ===== P6: greedy scan (block 0, wave 0) =====
    if (blk == 0 && tid < 64) {
        int q = lane >> 4, wrd = lane & 15;
        uint64_t remv = 0ull;
        uint64_t dcur = diag[lane];
        for (int g = 0; g < 16; ++g) {
            uint64_t dnxt = (g < 15) ? diag[64 * (g + 1) + lane] : 0ull;
            uint64_t bun[16];
            if (g < 15) {
#pragma unroll
                for (int r4 = 0; r4 < 16; ++r4)
                    bun[r4] = mask[(size_t)(64 * g + 4 * r4 + q) * 16 + wrd];
            }
            uint32_t dlo = 0, dhi = 0;
#pragma unroll
            for (int qq = 0; qq < 4; ++qq) {
                dlo |= __builtin_amdgcn_readlane((uint32_t)remv, qq * 16 + g);
                dhi |= __builtin_amdgcn_readlane((uint32_t)(remv >> 32), qq * 16 + g);
            }
            uint64_t D = ((uint64_t)dhi << 32) | dlo;
#pragma unroll
            for (int b = 0; b < 64; ++b) {
                uint32_t tlo = __builtin_amdgcn_readlane((uint32_t)dcur, b);
                uint32_t thi = __builtin_amdgcn_readlane((uint32_t)(dcur >> 32), b);
                uint64_t T = ((uint64_t)thi << 32) | tlo;
                uint64_t sel = ((D >> b) & 1ull) - 1ull;   // ~0 if row kept
                D |= T & sel;
            }
            uint64_t keepg = ~D;
            int j = g * 64 + lane;
            if (j < K_TOP) out[6 * K_TOP + j] = (float)((keepg >> lane) & 1ull);
            if (g < 15) {
#pragma unroll
                for (int r4 = 0; r4 < 16; ++r4) {
                    uint32_t kb = (uint32_t)(keepg >> (4 * r4 + q)) & 1u;
                    uint64_t mm = 0ull - (uint64_t)kb;
                    remv |= bun[r4] & mm;
                }
            }
            dcur = dnxt;
        }
    }
}

extern "C" void kernel_launch(void* const* d_in, const int* in_sizes, int n_in,
                              void* d_out, int out_size, void* d_ws, size_t ws_size,
                              hipStream_t stream) {
    const float* hmp = (const float*)d_in[0];
    const float* reg = (const float*)d_in[1];
    const float* iou = (const float*)d_in[2];
    float* out = (float*)d_out;
    char* ws = (char*)d_ws;

    float*    scores = (float*)(ws + OFF_SCORES);
    uint32_t* labels = (uint32_t*)(ws + OFF_LABELS);
    uint32_t* hist   = (uint32_t*)(ws + OFF_HIST);
    uint32_t* meta   = (uint32_t*)(ws + OFF_META);
    uint64_t* keys   = (uint64_t*)(ws + OFF_KEYS);
    float*    boxes  = (float*)(ws + OFF_BOXES);
    uint32_t* lab1k  = (uint32_t*)(ws + OFF_LAB1K);
    uint64_t* mask   = (uint64_t*)(ws + OFF_MASK);
    uint64_t* diag   = (uint64_t*)(ws + OFF_DIAG);

    k_scores<<<dim3(N_ANCH * 4 / 256), dim3(256), 0, stream>>>(hmp, iou, scores, labels, hist, meta, diag);
    k_mega<<<dim3(NBLK2), dim3(NTHR2), 0, stream>>>(scores, labels, reg, hist, meta,
                                                    keys, boxes, lab1k, mask, diag, out);
}

// Round 10
// 281.370 us; speedup vs baseline: 1.2042x; 1.2042x over previous
//
#include <hip/hip_runtime.h>
#include <stdint.h>

#define N_ANCH 102400
#define FMP 320
#define K_TOP 1000
#define NMS_T 0.6f
#define SC_CLAMP 6.907755278982137f
#define IMGF 1280.0f
#define NBINS 16384   // scores in (0,1) => float bits>>16 < 0x4000
#define NBLK2 100
#define NTHR2 1024

// ---- workspace layout (bytes) ----
#define OFF_SCORES   0u          // f32[102400]
#define OFF_LABELS   409600u     // u32[102400]
#define OFF_HIST     819200u     // u32[16384]
#define OFF_META     884736u     // u32[64]: [2]=cand ctr [8..10]=barrier counters
#define OFF_KEYS     884992u     // u64[4096]
#define OFF_BOXES    917760u     // f32[4000]
#define OFF_LAB1K    933760u     // u32[1000]
#define OFF_MASK     937760u     // u64[16000]
#define OFF_DIAG     1065760u    // u64[1024]

__device__ __forceinline__ float sigf(float x) {
    return 1.0f / (1.0f + expf(-x));
}

// Device-scope spin barrier for a co-resident grid (100 blocks on 256 CUs).
__device__ __forceinline__ void gbar(uint32_t* ctr, uint32_t target) {
    __threadfence();
    __syncthreads();
    if (threadIdx.x == 0) {
        atomicAdd(ctr, 1u);
        while (atomicAdd(ctr, 0u) < target) __builtin_amdgcn_s_sleep(10);
    }
    __syncthreads();
    __threadfence();
}

// ---------------- K1: scores+argmax; fused zeroing of hist/meta/diag ----------------
__global__ __launch_bounds__(256) void k_scores(const float* __restrict__ hmp,
                                                const float* __restrict__ iou,
                                                float* __restrict__ scores,
                                                uint32_t* __restrict__ labels,
                                                uint32_t* __restrict__ hist,
                                                uint32_t* __restrict__ meta,
                                                uint64_t* __restrict__ diag) {
    int blk = blockIdx.x;
    if (blk < 64) {
        hist[blk * 256 + threadIdx.x] = 0u;
    } else if (blk == 64) {
        if (threadIdx.x < 64) meta[threadIdx.x] = 0u;
#pragma unroll
        for (int k = 0; k < 4; ++k) diag[threadIdx.x * 4 + k] = 0ull;
    }
    int gid = blk * 256 + threadIdx.x;
    int a = gid >> 2;
    int q = gid & 3;
    float si = sigf(iou[a]);
    const float4* row4 = (const float4*)hmp + (size_t)a * 20 + q;
    float4 v[5];
#pragma unroll
    for (int j = 0; j < 5; ++j) v[j] = row4[j * 4];
    float best = -1.0f;
    int bc = 0;
#pragma unroll
    for (int j = 0; j < 5; ++j) {
        int cb = j * 16 + q * 4;
        float f;
        f = sqrtf(sigf(v[j].x) * si); if (f > best) { best = f; bc = cb; }
        f = sqrtf(sigf(v[j].y) * si); if (f > best) { best = f; bc = cb + 1; }
        f = sqrtf(sigf(v[j].z) * si); if (f > best) { best = f; bc = cb + 2; }
        f = sqrtf(sigf(v[j].w) * si); if (f > best) { best = f; bc = cb + 3; }
    }
#pragma unroll
    for (int off = 1; off <= 2; off <<= 1) {
        float of = __shfl_xor(best, off);
        int   oc = __shfl_xor(bc, off);
        if (of > best || (of == best && oc < bc)) { best = of; bc = oc; }
    }
    if (q == 0) {
        scores[a] = best;
        labels[a] = (uint32_t)bc;
    }
}

// ---------------- K2: hist+cutoff+collect+rank+mask, 100 blocks, 3 barriers ----------------
// No large per-lane arrays anywhere -> no spill hazard (R9's P6-in-fused
// kernel compiled at VGPR=40 and scratch-spilled the scan: 270us).
__global__ __launch_bounds__(NTHR2) void k_mega(const float* __restrict__ scores,
                                                const uint32_t* __restrict__ labels,
                                                const float* __restrict__ reg,
                                                uint32_t* __restrict__ hist,
                                                uint32_t* __restrict__ meta,
                                                uint64_t* __restrict__ keys,
                                                float* __restrict__ boxes,
                                                uint32_t* __restrict__ lab1k,
                                                uint64_t* __restrict__ mask,
                                                uint64_t* __restrict__ diag,
                                                float* __restrict__ out) {
    __shared__ __align__(16) uint32_t sh32[NBINS];   // 64 KB, reused per phase
    uint64_t* sk = (uint64_t*)sh32;                  // phase-4 view (4096 u64)
    const int tid  = threadIdx.x;
    const int blk  = blockIdx.x;
    const int gtid = blk * NTHR2 + tid;              // exactly covers 102400
    const int lane = tid & 63;
    const int wv   = tid >> 6;

    // ===== P1: LDS-private histogram of this block's 1024 scores =====
    for (int i = tid; i < NBINS; i += NTHR2) sh32[i] = 0u;
    __syncthreads();
    uint32_t mybits = __float_as_uint(scores[gtid]);
    atomicAdd(&sh32[mybits >> 16], 1u);
    __syncthreads();
    for (int i = tid; i < NBINS; i += NTHR2) {
        uint32_t c = sh32[i];
        if (c) atomicAdd(&hist[i], c);
    }
    gbar(&meta[8], NBLK2);   // ---- global hist complete

    // ===== P2: cutoff, computed redundantly by every block (no extra barrier) =====
    {
        uint32_t s = 0;
#pragma unroll
        for (int b = 0; b < 16; ++b) s += hist[tid * 16 + b];
        sh32[tid] = s;
        __syncthreads();
        for (int off = 1; off < NTHR2; off <<= 1) {
            uint32_t v = sh32[tid] + ((tid + off < NTHR2) ? sh32[tid + off] : 0u);
            __syncthreads();
            sh32[tid] = v;
            __syncthreads();
        }
        uint32_t inc   = sh32[tid];
        uint32_t above = (tid < NTHR2 - 1) ? sh32[tid + 1] : 0u;
        if (above < K_TOP && inc >= K_TOP) {
            uint32_t loc[16];
#pragma unroll
            for (int b = 0; b < 16; ++b) loc[b] = hist[tid * 16 + b];
            uint32_t cnt = above;
            for (int b = 15; b >= 0; --b) {
                cnt += loc[b];
                if (cnt >= K_TOP) { sh32[1025] = (uint32_t)(tid * 16 + b); break; }
            }
        }
        __syncthreads();
    }
    uint32_t cutoff = sh32[1025];
    __syncthreads();

    // ===== P3: collect this block's candidates (block-aggregated append) =====
    if (tid == 0) sh32[0] = 0u;
    __syncthreads();
    bool cand = (mybits >> 16) >= cutoff;
    uint32_t pos = 0;
    if (cand) pos = atomicAdd(&sh32[0], 1u);
    __syncthreads();
    if (tid == 0) sh32[1] = sh32[0] ? atomicAdd(&meta[2], sh32[0]) : 0u;
    __syncthreads();
    if (cand) {
        uint32_t p = sh32[1] + pos;
        if (p < 4096u)
            keys[p] = ((uint64_t)mybits << 32) | (uint64_t)(0xFFFFFFFFu - (uint32_t)gtid);
    }
    gbar(&meta[9], NBLK2);   // ---- keys complete

    // ===== P4: rank (wave per candidate) + decode epilogue =====
    {
        uint32_t M = meta[2];
        if (M > 4096u) M = 4096u;
        for (uint32_t i = tid; i < M; i += NTHR2) sk[i] = keys[i];
        __syncthreads();
        for (uint32_t wg = (uint32_t)(blk * 16 + wv); wg < M; wg += NBLK2 * 16) {
            uint64_t mykey = sk[wg];
            uint32_t rank = 0;
            for (uint32_t j = lane; j < M; j += 64) rank += (sk[j] > mykey) ? 1u : 0u;
#pragma unroll
            for (int off = 32; off; off >>= 1) rank += __shfl_xor(rank, off);
            if (lane == 0 && rank < K_TOP) {
                int t = (int)rank;
                uint32_t sbits = (uint32_t)(mykey >> 32);
                uint32_t idx   = 0xFFFFFFFFu - (uint32_t)(mykey & 0xFFFFFFFFull);
                float score = __uint_as_float(sbits);
                uint32_t lab = labels[idx];
                out[t]         = score;
                out[K_TOP + t] = (float)lab;
                lab1k[t]       = lab;
                float ax = (float)(idx % FMP);
                float ay = (float)(idx / FMP);
                float4 rr = ((const float4*)reg)[idx];
                float e0 = expf(fminf(rr.x, SC_CLAMP));
                float e1 = expf(fminf(rr.y, SC_CLAMP));
                float e2 = expf(fminf(rr.z, SC_CLAMP));
                float e3 = expf(fminf(rr.w, SC_CLAMP));
                float x1 = fminf(fmaxf((ax - e0) * 4.0f / IMGF, 0.0f), 1.0f);
                float y1 = fminf(fmaxf((ay - e1) * 4.0f / IMGF, 0.0f), 1.0f);
                float x2 = fminf(fmaxf((ax + e2) * 4.0f / IMGF, 0.0f), 1.0f);
                float y2 = fminf(fmaxf((ay + e3) * 4.0f / IMGF, 0.0f), 1.0f);
                out[2 * K_TOP + t * 4 + 0] = x1;
                out[2 * K_TOP + t * 4 + 1] = y1;
                out[2 * K_TOP + t * 4 + 2] = x2;
                out[2 * K_TOP + t * 4 + 3] = y2;
                boxes[t * 4 + 0] = x1;
                boxes[t * 4 + 1] = y1;
                boxes[t * 4 + 2] = x2;
                boxes[t * 4 + 3] = y2;
            }
        }
    }
    gbar(&meta[10], NBLK2);   // ---- boxes/lab1k ready

    // ===== P5: suppress masks, one wave per row (1600 waves >= 1000 rows) =====
    {
        int r = blk * 16 + wv;
        if (r < K_TOP) {
            float4 bi = ((const float4*)boxes)[r];
            uint32_t li = lab1k[r];
            float areai = (bi.z - bi.x) * (bi.w - bi.y);
            int iw = r >> 6;
            uint64_t dw = 0ull;
#pragma unroll
            for (int w = 0; w < 16; ++w) {
                int j = w * 64 + lane;
                bool sup = false;
                if (j < K_TOP && j > r) {
                    float4 bj = ((const float4*)boxes)[j];
                    float areaj = (bj.z - bj.x) * (bj.w - bj.y);
                    float xx1 = fmaxf(bi.x, bj.x);
                    float yy1 = fmaxf(bi.y, bj.y);
                    float xx2 = fminf(bi.z, bj.z);
                    float yy2 = fminf(bi.w, bj.w);
                    float ww = fmaxf(1e-10f, xx2 - xx1);
                    float hh = fmaxf(1e-10f, yy2 - yy1);
                    float inter = ww * hh;
                    float iouv = inter / (areai + areaj - inter + 1e-10f);
                    sup = (iouv > NMS_T) && (li == lab1k[j]);
                }
                unsigned long long m = __ballot(sup);
                if (lane == 0) mask[(size_t)r * 16 + w] = (uint64_t)m;
                if (w == iw) dw = (uint64_t)m;
            }
            if (lane == 0) diag[r] = dw;
        }
    }
    // no trailing barrier: stream order protects k_scan
}

// ---------------- K3: greedy scan, single wave, own register budget ----------------
// MUST stay a standalone kernel: fused versions (R3/R5/R6/R9) all compiled
// at VGPR<=40 and scratch-spilled bun[16] -> 100-300us. Standalone with
// launch_bounds(64,1) it holds ~100 VGPRs and runs ~10us.
__global__ __launch_bounds__(64, 1) void k_scan(const uint64_t* __restrict__ mask,
                                                const uint64_t* __restrict__ diag,
                                                float* __restrict__ out) {
    int lane = threadIdx.x;
    int q = lane >> 4, wrd = lane & 15;
    uint64_t remv = 0ull;
    uint64_t dcur = diag[lane];
    for (int g = 0; g < 16; ++g) {
        uint64_t dnxt = (g < 15) ? diag[64 * (g + 1) + lane] : 0ull;
        uint64_t bun[16];
        if (g < 15) {
#pragma unroll
            for (int r4 = 0; r4 < 16; ++r4)
                bun[r4] = mask[(size_t)(64 * g + 4 * r4 + q) * 16 + wrd];
        }
        uint32_t dlo = 0, dhi = 0;
#pragma unroll
        for (int qq = 0; qq < 4; ++qq) {
            dlo |= __builtin_amdgcn_readlane((uint32_t)remv, qq * 16 + g);
            dhi |= __builtin_amdgcn_readlane((uint32_t)(remv >> 32), qq * 16 + g);
        }
        uint64_t D = ((uint64_t)dhi << 32) | dlo;
#pragma unroll
        for (int b = 0; b < 64; ++b) {
            uint32_t tlo = __builtin_amdgcn_readlane((uint32_t)dcur, b);
            uint32_t thi = __builtin_amdgcn_readlane((uint32_t)(dcur >> 32), b);
            uint64_t T = ((uint64_t)thi << 32) | tlo;
            uint64_t sel = ((D >> b) & 1ull) - 1ull;   // ~0 if row kept
            D |= T & sel;
        }
        uint64_t keepg = ~D;
        int j = g * 64 + lane;
        if (j < K_TOP) out[6 * K_TOP + j] = (float)((keepg >> lane) & 1ull);
        if (g < 15) {
#pragma unroll
            for (int r4 = 0; r4 < 16; ++r4) {
                uint32_t kb = (uint32_t)(keepg >> (4 * r4 + q)) & 1u;
                uint64_t mm = 0ull - (uint64_t)kb;
                remv |= bun[r4] & mm;
            }
        }
        dcur = dnxt;
    }
}

extern "C" void kernel_launch(void* const* d_in, const int* in_sizes, int n_in,
                              void* d_out, int out_size, void* d_ws, size_t ws_size,
                              hipStream_t stream) {
    const float* hmp = (const float*)d_in[0];
    const float* reg = (const float*)d_in[1];
    const float* iou = (const float*)d_in[2];
    float* out = (float*)d_out;
    char* ws = (char*)d_ws;

    float*    scores = (float*)(ws + OFF_SCORES);
    uint32_t* labels = (uint32_t*)(ws + OFF_LABELS);
    uint32_t* hist   = (uint32_t*)(ws + OFF_HIST);
    uint32_t* meta   = (uint32_t*)(ws + OFF_META);
    uint64_t* keys   = (uint64_t*)(ws + OFF_KEYS);
    float*    boxes  = (float*)(ws + OFF_BOXES);
    uint32_t* lab1k  = (uint32_t*)(ws + OFF_LAB1K);
    uint64_t* mask   = (uint64_t*)(ws + OFF_MASK);
    uint64_t* diag   = (uint64_t*)(ws + OFF_DIAG);

    k_scores<<<dim3(N_ANCH * 4 / 256), dim3(256), 0, stream>>>(hmp, iou, scores, labels, hist, meta, diag);
    k_mega<<<dim3(NBLK2), dim3(NTHR2), 0, stream>>>(scores, labels, reg, hist, meta,
                                                    keys, boxes, lab1k, mask, diag, out);
    k_scan<<<dim3(1), dim3(64), 0, stream>>>(mask, diag, out);
}

// Round 11
// 224.801 us; speedup vs baseline: 1.5072x; 1.2516x over previous
//
#include <hip/hip_runtime.h>
#include <stdint.h>

#define N_ANCH 102400
#define FMP 320
#define K_TOP 1000
#define NMS_T 0.6f
#define SC_CLAMP 6.907755278982137f
#define IMGF 1280.0f
#define NBINS 16384   // scores in (0,1) => float bits>>16 < 0x4000

// ---- workspace layout (bytes) ----
#define OFF_SCORES   0u          // f32[102400]
#define OFF_LABELS   409600u     // u32[102400]
#define OFF_HIST     819200u     // u32[16384]
#define OFF_META     884736u     // u32[64]: [8]=hist arrive counter
#define OFF_BOXES    917760u     // f32[4000]
#define OFF_LAB1K    933760u     // u32[1000]
#define OFF_MASK     937760u     // u64[16000]
#define OFF_DIAG     1065760u    // u64[1024]

__device__ __forceinline__ float sigf(float x) {
    return 1.0f / (1.0f + expf(-x));
}

// ---------------- K1: scores+argmax; fused zeroing of hist/meta/diag ----------------
__global__ __launch_bounds__(256) void k_scores(const float* __restrict__ hmp,
                                                const float* __restrict__ iou,
                                                float* __restrict__ scores,
                                                uint32_t* __restrict__ labels,
                                                uint32_t* __restrict__ hist,
                                                uint32_t* __restrict__ meta,
                                                uint64_t* __restrict__ diag) {
    int blk = blockIdx.x;
    if (blk < 64) {
        hist[blk * 256 + threadIdx.x] = 0u;
    } else if (blk == 64) {
        if (threadIdx.x < 64) meta[threadIdx.x] = 0u;
#pragma unroll
        for (int k = 0; k < 4; ++k) diag[threadIdx.x * 4 + k] = 0ull;
    }
    int gid = blk * 256 + threadIdx.x;
    int a = gid >> 2;
    int q = gid & 3;
    float si = sigf(iou[a]);
    const float4* row4 = (const float4*)hmp + (size_t)a * 20 + q;
    float4 v[5];
#pragma unroll
    for (int j = 0; j < 5; ++j) v[j] = row4[j * 4];
    float best = -1.0f;
    int bc = 0;
#pragma unroll
    for (int j = 0; j < 5; ++j) {
        int cb = j * 16 + q * 4;
        float f;
        f = sqrtf(sigf(v[j].x) * si); if (f > best) { best = f; bc = cb; }
        f = sqrtf(sigf(v[j].y) * si); if (f > best) { best = f; bc = cb + 1; }
        f = sqrtf(sigf(v[j].z) * si); if (f > best) { best = f; bc = cb + 2; }
        f = sqrtf(sigf(v[j].w) * si); if (f > best) { best = f; bc = cb + 3; }
    }
#pragma unroll
    for (int off = 1; off <= 2; off <<= 1) {
        float of = __shfl_xor(best, off);
        int   oc = __shfl_xor(bc, off);
        if (of > best || (of == best && oc < bc)) { best = of; bc = oc; }
    }
    if (q == 0) {
        scores[a] = best;
        labels[a] = (uint32_t)bc;
    }
}

// ---------------- K2: hist; last of 64 blocks: cutoff + collect + rank + decode ----------------
// Last-block arrive among 64 blocks is the one cross-block pattern that
// measured cheap (R7). Keys live only in this block's LDS (no global keys).
__global__ __launch_bounds__(1024) void k_hist(const float* __restrict__ scores,
                                               const uint32_t* __restrict__ labels,
                                               const float* __restrict__ reg,
                                               uint32_t* __restrict__ hist,
                                               uint32_t* __restrict__ meta,
                                               float* __restrict__ out,
                                               float* __restrict__ boxes,
                                               uint32_t* __restrict__ lab1k) {
    __shared__ __align__(16) uint32_t lh[NBINS];   // 64 KB, reused per phase
    __shared__ int lastFlag;
    __shared__ uint32_t s_cut, s_cnt;
    const int t = threadIdx.x;

    // ---- P1: LDS-private histogram of this block's 1600 scores ----
    for (int i = t; i < NBINS; i += 1024) lh[i] = 0u;
    __syncthreads();
    int base = blockIdx.x * 1600;
    for (int k = t; k < 1600; k += 1024)
        atomicAdd(&lh[__float_as_uint(scores[base + k]) >> 16], 1u);
    __syncthreads();
    for (int i = t; i < NBINS; i += 1024) {
        uint32_t c = lh[i];
        if (c) atomicAdd(&hist[i], c);
    }
    __threadfence();
    __syncthreads();
    if (t == 0) lastFlag = (atomicAdd(&meta[8], 1u) == 63u);
    __syncthreads();
    if (!lastFlag) return;
    __threadfence();

    // ---- P2: cutoff (largest bin B with count(bin >= B) >= K_TOP) ----
    {
        uint32_t s = 0;
#pragma unroll
        for (int b = 0; b < 16; ++b) s += hist[t * 16 + b];
        lh[t] = s;
        __syncthreads();
        for (int off = 1; off < 1024; off <<= 1) {
            uint32_t v = lh[t] + ((t + off < 1024) ? lh[t + off] : 0u);
            __syncthreads();
            lh[t] = v;
            __syncthreads();
        }
        uint32_t inc   = lh[t];
        uint32_t above = (t < 1023) ? lh[t + 1] : 0u;
        if (above < K_TOP && inc >= K_TOP) {
            uint32_t loc[16];
#pragma unroll
            for (int b = 0; b < 16; ++b) loc[b] = hist[t * 16 + b];
            uint32_t cnt = above;
            for (int b = 15; b >= 0; --b) {
                cnt += loc[b];
                if (cnt >= K_TOP) { s_cut = (uint32_t)(t * 16 + b); break; }
            }
        }
        __syncthreads();
    }
    uint32_t cutoff = s_cut;
    __syncthreads();

    // ---- P3: collect candidate keys into LDS ----
    uint64_t* sk = (uint64_t*)lh;          // 4096 u64 = 32 KB
    if (t == 0) s_cnt = 0u;
    __syncthreads();
    for (int k = t; k < N_ANCH; k += 1024) {
        uint32_t bits = __float_as_uint(scores[k]);
        if ((bits >> 16) >= cutoff) {
            uint32_t p = atomicAdd(&s_cnt, 1u);
            if (p < 4096u)
                sk[p] = ((uint64_t)bits << 32) | (uint64_t)(0xFFFFFFFFu - (uint32_t)k);
        }
    }
    __syncthreads();
    uint32_t M = s_cnt;
    if (M > 4096u) M = 4096u;

    // ---- P4: rank (broadcast-read compares, conflict-free) + decode ----
    for (uint32_t c = t; c < M; c += 1024) {
        uint64_t mykey = sk[c];
        uint32_t rank = 0;
        uint32_t j = 0;
        for (; j + 4 <= M; j += 4) {
#pragma unroll
            for (int u = 0; u < 4; ++u) rank += (sk[j + u] > mykey) ? 1u : 0u;
        }
        for (; j < M; ++j) rank += (sk[j] > mykey) ? 1u : 0u;
        if (rank >= K_TOP) continue;
        int r = (int)rank;
        uint32_t sbits = (uint32_t)(mykey >> 32);
        uint32_t idx   = 0xFFFFFFFFu - (uint32_t)(mykey & 0xFFFFFFFFull);
        float score = __uint_as_float(sbits);
        uint32_t lab = labels[idx];
        out[r]         = score;
        out[K_TOP + r] = (float)lab;
        lab1k[r]       = lab;
        float ax = (float)(idx % FMP);
        float ay = (float)(idx / FMP);
        float4 rr = ((const float4*)reg)[idx];
        float e0 = expf(fminf(rr.x, SC_CLAMP));
        float e1 = expf(fminf(rr.y, SC_CLAMP));
        float e2 = expf(fminf(rr.z, SC_CLAMP));
        float e3 = expf(fminf(rr.w, SC_CLAMP));
        float x1 = fminf(fmaxf((ax - e0) * 4.0f / IMGF, 0.0f), 1.0f);
        float y1 = fminf(fmaxf((ay - e1) * 4.0f / IMGF, 0.0f), 1.0f);
        float x2 = fminf(fmaxf((ax + e2) * 4.0f / IMGF, 0.0f), 1.0f);
        float y2 = fminf(fmaxf((ay + e3) * 4.0f / IMGF, 0.0f), 1.0f);
        out[2 * K_TOP + r * 4 + 0] = x1;
        out[2 * K_TOP + r * 4 + 1] = y1;
        out[2 * K_TOP + r * 4 + 2] = x2;
        out[2 * K_TOP + r * 4 + 3] = y2;
        boxes[r * 4 + 0] = x1;
        boxes[r * 4 + 1] = y1;
        boxes[r * 4 + 2] = x2;
        boxes[r * 4 + 3] = y2;
    }
}

// ---------------- K3: suppress masks, one wave per row (63 x 1024) ----------------
__global__ __launch_bounds__(1024) void k_mask(const float* __restrict__ boxes,
                                               const uint32_t* __restrict__ lab1k,
                                               uint64_t* __restrict__ mask,
                                               uint64_t* __restrict__ diag) {
    int r = blockIdx.x * 16 + (threadIdx.x >> 6);
    int lane = threadIdx.x & 63;
    if (r >= K_TOP) return;
    float4 bi = ((const float4*)boxes)[r];
    uint32_t li = lab1k[r];
    float areai = (bi.z - bi.x) * (bi.w - bi.y);
    int iw = r >> 6;
    uint64_t dw = 0ull;
#pragma unroll
    for (int w = 0; w < 16; ++w) {
        int j = w * 64 + lane;
        bool sup = false;
        if (j < K_TOP && j > r) {
            float4 bj = ((const float4*)boxes)[j];
            float areaj = (bj.z - bj.x) * (bj.w - bj.y);
            float xx1 = fmaxf(bi.x, bj.x);
            float yy1 = fmaxf(bi.y, bj.y);
            float xx2 = fminf(bi.z, bj.z);
            float yy2 = fminf(bi.w, bj.w);
            float ww = fmaxf(1e-10f, xx2 - xx1);
            float hh = fmaxf(1e-10f, yy2 - yy1);
            float inter = ww * hh;
            float iouv = inter / (areai + areaj - inter + 1e-10f);
            sup = (iouv > NMS_T) && (li == lab1k[j]);
        }
        unsigned long long m = __ballot(sup);
        if (lane == 0) mask[(size_t)r * 16 + w] = (uint64_t)m;
        if (w == iw) dw = (uint64_t)m;
    }
    if (lane == 0) diag[r] = dw;
}

// ---------------- K4: greedy scan, single wave, own register budget ----------------
// MUST stay standalone: fused variants (R3/R5/R6/R9) all compiled at
// VGPR<=40 and scratch-spilled bun[16] -> 100-300us.
__global__ __launch_bounds__(64, 1) void k_scan(const uint64_t* __restrict__ mask,
                                                const uint64_t* __restrict__ diag,
                                                float* __restrict__ out) {
    int lane = threadIdx.x;
    int q = lane >> 4, wrd = lane & 15;
    uint64_t remv = 0ull;
    uint64_t dcur = diag[lane];
    for (int g = 0; g < 16; ++g) {
        uint64_t dnxt = (g < 15) ? diag[64 * (g + 1) + lane] : 0ull;
        uint64_t bun[16];
        if (g < 15) {
#pragma unroll
            for (int r4 = 0; r4 < 16; ++r4)
                bun[r4] = mask[(size_t)(64 * g + 4 * r4 + q) * 16 + wrd];
        }
        uint32_t dlo = 0, dhi = 0;
#pragma unroll
        for (int qq = 0; qq < 4; ++qq) {
            dlo |= __builtin_amdgcn_readlane((uint32_t)remv, qq * 16 + g);
            dhi |= __builtin_amdgcn_readlane((uint32_t)(remv >> 32), qq * 16 + g);
        }
        uint64_t D = ((uint64_t)dhi << 32) | dlo;
#pragma unroll
        for (int b = 0; b < 64; ++b) {
            uint32_t tlo = __builtin_amdgcn_readlane((uint32_t)dcur, b);
            uint32_t thi = __builtin_amdgcn_readlane((uint32_t)(dcur >> 32), b);
            uint64_t T = ((uint64_t)thi << 32) | tlo;
            uint64_t sel = ((D >> b) & 1ull) - 1ull;   // ~0 if row kept
            D |= T & sel;
        }
        uint64_t keepg = ~D;
        int j = g * 64 + lane;
        if (j < K_TOP) out[6 * K_TOP + j] = (float)((keepg >> lane) & 1ull);
        if (g < 15) {
#pragma unroll
            for (int r4 = 0; r4 < 16; ++r4) {
                uint32_t kb = (uint32_t)(keepg >> (4 * r4 + q)) & 1u;
                uint64_t mm = 0ull - (uint64_t)kb;
                remv |= bun[r4] & mm;
            }
        }
        dcur = dnxt;
    }
}

extern "C" void kernel_launch(void* const* d_in, const int* in_sizes, int n_in,
                              void* d_out, int out_size, void* d_ws, size_t ws_size,
                              hipStream_t stream) {
    const float* hmp = (const float*)d_in[0];
    const float* reg = (const float*)d_in[1];
    const float* iou = (const float*)d_in[2];
    float* out = (float*)d_out;
    char* ws = (char*)d_ws;

    float*    scores = (float*)(ws + OFF_SCORES);
    uint32_t* labels = (uint32_t*)(ws + OFF_LABELS);
    uint32_t* hist   = (uint32_t*)(ws + OFF_HIST);
    uint32_t* meta   = (uint32_t*)(ws + OFF_META);
    float*    boxes  = (float*)(ws + OFF_BOXES);
    uint32_t* lab1k  = (uint32_t*)(ws + OFF_LAB1K);
    uint64_t* mask   = (uint64_t*)(ws + OFF_MASK);
    uint64_t* diag   = (uint64_t*)(ws + OFF_DIAG);

    k_scores<<<dim3(N_ANCH * 4 / 256), dim3(256), 0, stream>>>(hmp, iou, scores, labels, hist, meta, diag);
    k_hist<<<dim3(64), dim3(1024), 0, stream>>>(scores, labels, reg, hist, meta, out, boxes, lab1k);
    k_mask<<<dim3(63), dim3(1024), 0, stream>>>(boxes, lab1k, mask, diag);
    k_scan<<<dim3(1), dim3(64), 0, stream>>>(mask, diag, out);
}

// Round 12
// 187.971 us; speedup vs baseline: 1.8025x; 1.1959x over previous
//
#include <hip/hip_runtime.h>
#include <stdint.h>

#define N_ANCH 102400
#define FMP 320
#define K_TOP 1000
#define NMS_T 0.6f
#define SC_CLAMP 6.907755278982137f
#define IMGF 1280.0f
#define NBINS 16384   // scores in (0,1) => float bits>>16 < 0x4000

// ---- workspace layout (bytes) ----
#define OFF_SCORES   0u          // f32[102400]
#define OFF_LABELS   409600u     // u32[102400]
#define OFF_HIST     819200u     // u32[16384]
#define OFF_META     884736u     // u32[64]: [0]=cutoff [8]=hist arrive counter
#define OFF_BOXES    917760u     // f32[4000]
#define OFF_LAB1K    933760u     // u32[1000]
#define OFF_MASK     937760u     // u64[16000]
#define OFF_DIAG     1065760u    // u64[1024]

__device__ __forceinline__ float sigf(float x) {
    return 1.0f / (1.0f + expf(-x));
}

// ---------------- K1: scores+argmax; fused zeroing of hist/meta/diag ----------------
__global__ __launch_bounds__(256) void k_scores(const float* __restrict__ hmp,
                                                const float* __restrict__ iou,
                                                float* __restrict__ scores,
                                                uint32_t* __restrict__ labels,
                                                uint32_t* __restrict__ hist,
                                                uint32_t* __restrict__ meta,
                                                uint64_t* __restrict__ diag) {
    int blk = blockIdx.x;
    if (blk < 64) {
        hist[blk * 256 + threadIdx.x] = 0u;
    } else if (blk == 64) {
        if (threadIdx.x < 64) meta[threadIdx.x] = 0u;
#pragma unroll
        for (int k = 0; k < 4; ++k) diag[threadIdx.x * 4 + k] = 0ull;
    }
    int gid = blk * 256 + threadIdx.x;
    int a = gid >> 2;
    int q = gid & 3;
    float si = sigf(iou[a]);
    const float4* row4 = (const float4*)hmp + (size_t)a * 20 + q;
    float4 v[5];
#pragma unroll
    for (int j = 0; j < 5; ++j) v[j] = row4[j * 4];
    float best = -1.0f;
    int bc = 0;
#pragma unroll
    for (int j = 0; j < 5; ++j) {
        int cb = j * 16 + q * 4;
        float f;
        f = sqrtf(sigf(v[j].x) * si); if (f > best) { best = f; bc = cb; }
        f = sqrtf(sigf(v[j].y) * si); if (f > best) { best = f; bc = cb + 1; }
        f = sqrtf(sigf(v[j].z) * si); if (f > best) { best = f; bc = cb + 2; }
        f = sqrtf(sigf(v[j].w) * si); if (f > best) { best = f; bc = cb + 3; }
    }
#pragma unroll
    for (int off = 1; off <= 2; off <<= 1) {
        float of = __shfl_xor(best, off);
        int   oc = __shfl_xor(bc, off);
        if (of > best || (of == best && oc < bc)) { best = of; bc = oc; }
    }
    if (q == 0) {
        scores[a] = best;
        labels[a] = (uint32_t)bc;
    }
}

// ---------------- K2: LDS-private histogram; last of 64 blocks finds cutoff ----------------
// (R7's proven version: hist + cutoff only, no tail work on global arrays.)
__global__ __launch_bounds__(1024) void k_hist(const float* __restrict__ scores,
                                               uint32_t* __restrict__ hist,
                                               uint32_t* __restrict__ meta) {
    __shared__ uint32_t lh[NBINS];
    __shared__ int lastFlag;
    for (int i = threadIdx.x; i < NBINS; i += 1024) lh[i] = 0u;
    __syncthreads();
    int base = blockIdx.x * 1600;
    for (int k = threadIdx.x; k < 1600; k += 1024)
        atomicAdd(&lh[__float_as_uint(scores[base + k]) >> 16], 1u);
    __syncthreads();
    for (int i = threadIdx.x; i < NBINS; i += 1024) {
        uint32_t c = lh[i];
        if (c) atomicAdd(&hist[i], c);
    }
    __threadfence();
    __syncthreads();
    if (threadIdx.x == 0) lastFlag = (atomicAdd(&meta[8], 1u) == 63u);
    __syncthreads();
    if (!lastFlag) return;
    __threadfence();
    int t = threadIdx.x;
    uint32_t s = 0;
#pragma unroll
    for (int b = 0; b < 16; ++b) s += hist[t * 16 + b];
    lh[t] = s;
    __syncthreads();
    for (int off = 1; off < 1024; off <<= 1) {
        uint32_t v = lh[t] + ((t + off < 1024) ? lh[t + off] : 0u);
        __syncthreads();
        lh[t] = v;
        __syncthreads();
    }
    uint32_t inc   = lh[t];
    uint32_t above = (t < 1023) ? lh[t + 1] : 0u;
    if (above < K_TOP && inc >= K_TOP) {
        uint32_t loc[16];
#pragma unroll
        for (int b = 0; b < 16; ++b) loc[b] = hist[t * 16 + b];
        uint32_t cnt = above;
        for (int b = 15; b >= 0; --b) {
            cnt += loc[b];
            if (cnt >= K_TOP) { meta[0] = (uint32_t)(t * 16 + b); break; }
        }
    }
}

// ---------------- K3: self-collecting rank + decode (64 blocks) ----------------
// Rank = #{keys > mine} is order-independent, so every block redundantly
// scans the full score array (25.6 MB total, L2/L3-resident, parallel across
// 64 CUs — NOT the single-block latency-bound tail that cost R11 90us),
// builds the full candidate list in its own LDS (any order), and ranks only
// candidates whose anchor idx is in its 1600-wide slice.
__global__ __launch_bounds__(1024) void k_rankall(const float* __restrict__ scores,
                                                  const uint32_t* __restrict__ meta,
                                                  const uint32_t* __restrict__ labels,
                                                  const float* __restrict__ reg,
                                                  float* __restrict__ out,
                                                  float* __restrict__ boxes,
                                                  uint32_t* __restrict__ lab1k) {
    __shared__ uint64_t sk[4096];
    __shared__ uint32_t s_cnt;
    const int tid = threadIdx.x;
    const int blk = blockIdx.x;
    if (tid == 0) s_cnt = 0u;
    __syncthreads();
    uint32_t cutoff = meta[0];
    // full scan: 25600 float4 / 1024 threads = 25 iters, coalesced
    const float4* s4 = (const float4*)scores;
#pragma unroll 5
    for (int it = 0; it < 25; ++it) {
        int e4 = it * 1024 + tid;
        float4 v = s4[e4];
        uint32_t b0 = __float_as_uint(v.x);
        uint32_t b1 = __float_as_uint(v.y);
        uint32_t b2 = __float_as_uint(v.z);
        uint32_t b3 = __float_as_uint(v.w);
        int idx = e4 * 4;
        if ((b0 >> 16) >= cutoff) { uint32_t p = atomicAdd(&s_cnt, 1u); if (p < 4096u) sk[p] = ((uint64_t)b0 << 32) | (uint64_t)(0xFFFFFFFFu - (uint32_t)(idx + 0)); }
        if ((b1 >> 16) >= cutoff) { uint32_t p = atomicAdd(&s_cnt, 1u); if (p < 4096u) sk[p] = ((uint64_t)b1 << 32) | (uint64_t)(0xFFFFFFFFu - (uint32_t)(idx + 1)); }
        if ((b2 >> 16) >= cutoff) { uint32_t p = atomicAdd(&s_cnt, 1u); if (p < 4096u) sk[p] = ((uint64_t)b2 << 32) | (uint64_t)(0xFFFFFFFFu - (uint32_t)(idx + 2)); }
        if ((b3 >> 16) >= cutoff) { uint32_t p = atomicAdd(&s_cnt, 1u); if (p < 4096u) sk[p] = ((uint64_t)b3 << 32) | (uint64_t)(0xFFFFFFFFu - (uint32_t)(idx + 3)); }
    }
    __syncthreads();
    uint32_t M = s_cnt;
    if (M > 4096u) M = 4096u;
    uint32_t lo = (uint32_t)blk * 1600u, hi = lo + 1600u;
    for (uint32_t e = tid; e < M; e += 1024) {
        uint64_t mykey = sk[e];
        uint32_t idx = 0xFFFFFFFFu - (uint32_t)(mykey & 0xFFFFFFFFull);
        if (idx < lo || idx >= hi) continue;       // not this block's slice
        uint32_t rank = 0;
        uint32_t j = 0;
        for (; j + 4 <= M; j += 4) {
#pragma unroll
            for (int u = 0; u < 4; ++u) rank += (sk[j + u] > mykey) ? 1u : 0u;
        }
        for (; j < M; ++j) rank += (sk[j] > mykey) ? 1u : 0u;
        if (rank >= K_TOP) continue;
        int r = (int)rank;
        float score = __uint_as_float((uint32_t)(mykey >> 32));
        uint32_t lab = labels[idx];
        out[r]         = score;
        out[K_TOP + r] = (float)lab;
        lab1k[r]       = lab;
        float ax = (float)(idx % FMP);
        float ay = (float)(idx / FMP);
        float4 rr = ((const float4*)reg)[idx];
        float e0 = expf(fminf(rr.x, SC_CLAMP));
        float e1 = expf(fminf(rr.y, SC_CLAMP));
        float e2 = expf(fminf(rr.z, SC_CLAMP));
        float e3 = expf(fminf(rr.w, SC_CLAMP));
        float x1 = fminf(fmaxf((ax - e0) * 4.0f / IMGF, 0.0f), 1.0f);
        float y1 = fminf(fmaxf((ay - e1) * 4.0f / IMGF, 0.0f), 1.0f);
        float x2 = fminf(fmaxf((ax + e2) * 4.0f / IMGF, 0.0f), 1.0f);
        float y2 = fminf(fmaxf((ay + e3) * 4.0f / IMGF, 0.0f), 1.0f);
        out[2 * K_TOP + r * 4 + 0] = x1;
        out[2 * K_TOP + r * 4 + 1] = y1;
        out[2 * K_TOP + r * 4 + 2] = x2;
        out[2 * K_TOP + r * 4 + 3] = y2;
        boxes[r * 4 + 0] = x1;
        boxes[r * 4 + 1] = y1;
        boxes[r * 4 + 2] = x2;
        boxes[r * 4 + 3] = y2;
    }
}

// ---------------- K4: suppress masks, one wave per row (63 x 1024) ----------------
__global__ __launch_bounds__(1024) void k_mask(const float* __restrict__ boxes,
                                               const uint32_t* __restrict__ lab1k,
                                               uint64_t* __restrict__ mask,
                                               uint64_t* __restrict__ diag) {
    int r = blockIdx.x * 16 + (threadIdx.x >> 6);
    int lane = threadIdx.x & 63;
    if (r >= K_TOP) return;
    float4 bi = ((const float4*)boxes)[r];
    uint32_t li = lab1k[r];
    float areai = (bi.z - bi.x) * (bi.w - bi.y);
    int iw = r >> 6;
    uint64_t dw = 0ull;
#pragma unroll
    for (int w = 0; w < 16; ++w) {
        int j = w * 64 + lane;
        bool sup = false;
        if (j < K_TOP && j > r) {
            float4 bj = ((const float4*)boxes)[j];
            float areaj = (bj.z - bj.x) * (bj.w - bj.y);
            float xx1 = fmaxf(bi.x, bj.x);
            float yy1 = fmaxf(bi.y, bj.y);
            float xx2 = fminf(bi.z, bj.z);
            float yy2 = fminf(bi.w, bj.w);
            float ww = fmaxf(1e-10f, xx2 - xx1);
            float hh = fmaxf(1e-10f, yy2 - yy1);
            float inter = ww * hh;
            float iouv = inter / (areai + areaj - inter + 1e-10f);
            sup = (iouv > NMS_T) && (li == lab1k[j]);
        }
        unsigned long long m = __ballot(sup);
        if (lane == 0) mask[(size_t)r * 16 + w] = (uint64_t)m;
        if (w == iw) dw = (uint64_t)m;
    }
    if (lane == 0) diag[r] = dw;
}

// ---------------- K5: greedy scan, single wave, own register budget ----------------
// MUST stay standalone: fused variants (R3/R5/R6/R9) all compiled at
// VGPR<=40 and scratch-spilled bun[16] -> 100-300us.
__global__ __launch_bounds__(64, 1) void k_scan(const uint64_t* __restrict__ mask,
                                                const uint64_t* __restrict__ diag,
                                                float* __restrict__ out) {
    int lane = threadIdx.x;
    int q = lane >> 4, wrd = lane & 15;
    uint64_t remv = 0ull;
    uint64_t dcur = diag[lane];
    for (int g = 0; g < 16; ++g) {
        uint64_t dnxt = (g < 15) ? diag[64 * (g + 1) + lane] : 0ull;
        uint64_t bun[16];
        if (g < 15) {
#pragma unroll
            for (int r4 = 0; r4 < 16; ++r4)
                bun[r4] = mask[(size_t)(64 * g + 4 * r4 + q) * 16 + wrd];
        }
        uint32_t dlo = 0, dhi = 0;
#pragma unroll
        for (int qq = 0; qq < 4; ++qq) {
            dlo |= __builtin_amdgcn_readlane((uint32_t)remv, qq * 16 + g);
            dhi |= __builtin_amdgcn_readlane((uint32_t)(remv >> 32), qq * 16 + g);
        }
        uint64_t D = ((uint64_t)dhi << 32) | dlo;
#pragma unroll
        for (int b = 0; b < 64; ++b) {
            uint32_t tlo = __builtin_amdgcn_readlane((uint32_t)dcur, b);
            uint32_t thi = __builtin_amdgcn_readlane((uint32_t)(dcur >> 32), b);
            uint64_t T = ((uint64_t)thi << 32) | tlo;
            uint64_t sel = ((D >> b) & 1ull) - 1ull;   // ~0 if row kept
            D |= T & sel;
        }
        uint64_t keepg = ~D;
        int j = g * 64 + lane;
        if (j < K_TOP) out[6 * K_TOP + j] = (float)((keepg >> lane) & 1ull);
        if (g < 15) {
#pragma unroll
            for (int r4 = 0; r4 < 16; ++r4) {
                uint32_t kb = (uint32_t)(keepg >> (4 * r4 + q)) & 1u;
                uint64_t mm = 0ull - (uint64_t)kb;
                remv |= bun[r4] & mm;
            }
        }
        dcur = dnxt;
    }
}

extern "C" void kernel_launch(void* const* d_in, const int* in_sizes, int n_in,
                              void* d_out, int out_size, void* d_ws, size_t ws_size,
                              hipStream_t stream) {
    const float* hmp = (const float*)d_in[0];
    const float* reg = (const float*)d_in[1];
    const float* iou = (const float*)d_in[2];
    float* out = (float*)d_out;
    char* ws = (char*)d_ws;

    float*    scores = (float*)(ws + OFF_SCORES);
    uint32_t* labels = (uint32_t*)(ws + OFF_LABELS);
    uint32_t* hist   = (uint32_t*)(ws + OFF_HIST);
    uint32_t* meta   = (uint32_t*)(ws + OFF_META);
    float*    boxes  = (float*)(ws + OFF_BOXES);
    uint32_t* lab1k  = (uint32_t*)(ws + OFF_LAB1K);
    uint64_t* mask   = (uint64_t*)(ws + OFF_MASK);
    uint64_t* diag   = (uint64_t*)(ws + OFF_DIAG);

    k_scores<<<dim3(N_ANCH * 4 / 256), dim3(256), 0, stream>>>(hmp, iou, scores, labels, hist, meta, diag);
    k_hist<<<dim3(64), dim3(1024), 0, stream>>>(scores, hist, meta);
    k_rankall<<<dim3(64), dim3(1024), 0, stream>>>(scores, meta, labels, reg, out, boxes, lab1k);
    k_mask<<<dim3(63), dim3(1024), 0, stream>>>(boxes, lab1k, mask, diag);
    k_scan<<<dim3(1), dim3(64), 0, stream>>>(mask, diag, out);
}